// Round 1
// 68.244 us; speedup vs baseline: 1.0130x; 1.0130x over previous
//
#include <hip/hip_runtime.h>
#include <hip/hip_bf16.h>
#include <math.h>

#define LN_EPS 1e-5f

constexpr int BB  = 4;
constexpr int NS  = 1024;
constexpr int KP  = 8192;
constexpr int DV  = 768;
constexpr int DC  = 256;

using bf16x8 = __attribute__((ext_vector_type(8))) short;
using f32x4  = __attribute__((ext_vector_type(4))) float;

static __device__ __forceinline__ unsigned short f2bf(float v) {
    __hip_bfloat16 h = __float2bfloat16(v);
    return *reinterpret_cast<unsigned short*>(&h);
}

// ---------------------------------------------------------------------------
// K1: blocks [0,512)   : argmin — 8 seeds/block, each thread reads a point
//     once from LDS and scores it against all 8 seeds (f64-exact ordering
//     via monotone form |p|^2 - 2 s.p ; normalization cancels in argmin).
//     blocks [512,832) : weight f32->bf16 conversion (1 float4/thread).
// ---------------------------------------------------------------------------
__global__ __launch_bounds__(256) void argmin_prep_kernel(
    const float* __restrict__ seed_xyz, const float* __restrict__ pts,
    int* __restrict__ out_idx,
    const float* __restrict__ Wp, const float* __restrict__ W1,
    const float* __restrict__ W2,
    unsigned short* __restrict__ Wpb, unsigned short* __restrict__ W1b,
    unsigned short* __restrict__ W2b)
{
    const int t = threadIdx.x;
    if (blockIdx.x >= 512) {
        int e  = (blockIdx.x - 512) * 256 + t;   // float4 id, 81920 total
        int e4 = e << 2;
        const float* src; unsigned short* dst; int off;
        if (e4 < DC * DV)              { src = Wp; dst = Wpb; off = e4; }
        else if (e4 < DC * (DV + DC))  { src = W1; dst = W1b; off = e4 - DC * DV; }
        else                           { src = W2; dst = W2b; off = e4 - DC * (DV + DC); }
        float4 v = *(const float4*)(src + off);
        ushort4 o;
        o.x = f2bf(v.x); o.y = f2bf(v.y); o.z = f2bf(v.z); o.w = f2bf(v.w);
        *(ushort4*)(dst + off) = o;
        return;
    }

    __shared__ float shX[1024], shY[1024], shZ[1024];
    __shared__ double rb[4][8];
    __shared__ int    ri[4][8];

    const int bid  = blockIdx.x;
    const int b    = bid >> 7;          // 128 tiles per batch
    const int tile = bid & 127;

    // 8 seeds of this block, premultiplied by -2 (f64)
    double n2sx[8], n2sy[8], n2sz[8];
    {
        const float* sp = seed_xyz + ((size_t)b * NS + tile * 8) * 3;
        #pragma unroll
        for (int ss = 0; ss < 8; ++ss) {
            n2sx[ss] = -2.0 * (double)sp[ss * 3 + 0];
            n2sy[ss] = -2.0 * (double)sp[ss * 3 + 1];
            n2sz[ss] = -2.0 * (double)sp[ss * 3 + 2];
        }
    }

    const float* pb = pts + (size_t)b * KP * 3;
    double best[8];
    int    bidx[8];
    #pragma unroll
    for (int ss = 0; ss < 8; ++ss) { best[ss] = 1e300; bidx[ss] = 0; }

    for (int kt = 0; kt < KP; kt += 1024) {
        #pragma unroll
        for (int q = 0; q < 4; ++q) {
            int i = t + q * 256;
            const float* pp = pb + (size_t)(kt + i) * 3;
            shX[i] = pp[0]; shY[i] = pp[1]; shZ[i] = pp[2];
        }
        __syncthreads();
        #pragma unroll 2
        for (int q = 0; q < 4; ++q) {
            int kl = t + (q << 8);              // stride-1 per lane: conflict-free
            double px = (double)shX[kl];
            double py = (double)shY[kl];
            double pz = (double)shZ[kl];
            double h  = fma(px, px, fma(py, py, pz * pz));   // |p|^2
            #pragma unroll
            for (int ss = 0; ss < 8; ++ss) {
                double acc = fma(n2sx[ss], px, h);
                acc = fma(n2sy[ss], py, acc);
                acc = fma(n2sz[ss], pz, acc);
                if (acc < best[ss]) { best[ss] = acc; bidx[ss] = kt + kl; }
            }
        }
        __syncthreads();
    }

    // intra-wave reduce (lexicographic: min d2, tie -> min idx)
    #pragma unroll
    for (int o = 1; o < 64; o <<= 1) {
        #pragma unroll
        for (int ss = 0; ss < 8; ++ss) {
            double ob = __shfl_xor(best[ss], o);
            int    oi = __shfl_xor(bidx[ss], o);
            if (ob < best[ss] || (ob == best[ss] && oi < bidx[ss])) {
                best[ss] = ob; bidx[ss] = oi;
            }
        }
    }
    const int w = t >> 6, l = t & 63;
    if (l == 0) {
        #pragma unroll
        for (int ss = 0; ss < 8; ++ss) { rb[w][ss] = best[ss]; ri[w][ss] = bidx[ss]; }
    }
    __syncthreads();
    if (t < 8) {
        double bb = rb[0][t]; int bi = ri[0][t];
        #pragma unroll
        for (int ww = 1; ww < 4; ++ww) {
            double ob = rb[ww][t]; int oi = ri[ww][t];
            if (ob < bb || (ob == bb && oi < bi)) { bb = ob; bi = oi; }
        }
        out_idx[b * NS + tile * 8 + t] = bi;
    }
}

// ---------------------------------------------------------------------------
// K3': fused sort+gather. grid = (batch x 64 channel-groups of 12),
// 512 threads (8 waves/CU — 2x the old concurrency for the scattered reads).
// Prologue: block-local counting sort of the batch's 1024 seed indices by
// cache line (k>>4, 512 buckets) entirely in LDS — removes the standalone
// 4-block sort kernel and its launch gap. Then each needed line of this
// block's 12 channel rows is fetched once, in ascending-address order.
// Writes Gb[b][seed][c] (bf16) at original seed position (order-invariant).
// ---------------------------------------------------------------------------
__global__ __launch_bounds__(512) void gather_kernel(
    const float* __restrict__ feat, const int* __restrict__ idx,
    unsigned short* __restrict__ Gb)
{
    __shared__ int h[512], sc[512], base[512], cnt[512];
    __shared__ int ordL[1024];
    __shared__ int ksL[1024];

    const int bid = blockIdx.x;
    const int b   = bid >> 6;
    const int cg  = bid & 63;
    const int c0  = cg * 12;
    const int t   = threadIdx.x;

    // ---- in-block counting sort by cache line ----
    h[t] = 0; cnt[t] = 0;
    __syncthreads();
    const int k0 = idx[b * NS + t];
    const int k1 = idx[b * NS + 512 + t];
    atomicAdd(&h[k0 >> 4], 1);
    atomicAdd(&h[k1 >> 4], 1);
    __syncthreads();
    sc[t] = h[t];
    __syncthreads();
    for (int st = 1; st < 512; st <<= 1) {       // inclusive Hillis-Steele
        int add = (t >= st) ? sc[t - st] : 0;
        __syncthreads();
        sc[t] += add;
        __syncthreads();
    }
    base[t] = sc[t] - h[t];                      // exclusive
    __syncthreads();
    {
        int bk = k0 >> 4;
        int p  = base[bk] + atomicAdd(&cnt[bk], 1);
        ordL[p] = t;
        ksL [p] = k0;
    }
    {
        int bk = k1 >> 4;
        int p  = base[bk] + atomicAdd(&cnt[bk], 1);
        ordL[p] = 512 + t;
        ksL [p] = k1;
    }
    __syncthreads();

    // ---- gather: 2 sorted positions x 12 channels per thread (24 loads) ----
    const float* fb = feat + ((size_t)b * DV + c0) * KP;

    int sA[2], kA[2];
    #pragma unroll
    for (int i = 0; i < 2; ++i) {
        sA[i] = ordL[t + i * 512];
        kA[i] = ksL [t + i * 512];
    }
    float v[2][12];
    #pragma unroll
    for (int i = 0; i < 2; ++i)
        #pragma unroll
        for (int c = 0; c < 12; ++c)
            v[i][c] = fb[(size_t)c * KP + kA[i]];

    #pragma unroll
    for (int i = 0; i < 2; ++i) {
        ushort4 o0, o1, o2;
        o0.x = f2bf(v[i][0]);  o0.y = f2bf(v[i][1]);
        o0.z = f2bf(v[i][2]);  o0.w = f2bf(v[i][3]);
        o1.x = f2bf(v[i][4]);  o1.y = f2bf(v[i][5]);
        o1.z = f2bf(v[i][6]);  o1.w = f2bf(v[i][7]);
        o2.x = f2bf(v[i][8]);  o2.y = f2bf(v[i][9]);
        o2.z = f2bf(v[i][10]); o2.w = f2bf(v[i][11]);
        unsigned short* g = Gb + ((size_t)b * NS + sA[i]) * DV + c0;
        *(ushort4*)(g)     = o0;
        *(ushort4*)(g + 4) = o1;
        *(ushort4*)(g + 8) = o2;
    }
}

// ---------------------------------------------------------------------------
// K4: mega GEMM chain. per block = (batch, 16 seeds), 8 waves.
// MFMA frag: A row=lane&15,k=(lane>>4)*8+j ; B col=lane&15; C/D col=lane&15,
// row=(lane>>4)*4+reg. New: fg blend operand prefetched into registers at
// kernel start so its HBM latency hides under the whole GEMM chain.
// ---------------------------------------------------------------------------
__global__ __launch_bounds__(512) void mega_kernel(
    const unsigned short* __restrict__ Gb,
    const float* __restrict__ fg,
    const unsigned short* __restrict__ Wpb, const float* __restrict__ bp,
    const unsigned short* __restrict__ W1b, const float* __restrict__ b1,
    const unsigned short* __restrict__ W2b, const float* __restrict__ b2,
    float* __restrict__ out)
{
    __shared__ alignas(16) unsigned short GtT[16][776];
    __shared__ alignas(16) unsigned short XT[16][264];
    __shared__ alignas(16) unsigned short HT[16][264];
    __shared__ float LNs[8][16];
    __shared__ float LNq[8][16];

    const int bid  = blockIdx.x;
    const int b    = bid >> 6;
    const int tile = bid & 63;
    const int n0   = tile * 16;
    const int t    = threadIdx.x;
    const int w    = t >> 6;
    const int l    = t & 63;
    const int col  = l & 15;
    const int kq   = l >> 4;

    // prefetch blend operand (consumed in epilogue; latency hidden by GEMMs)
    const float* fgb = fg + (size_t)b * DC * NS;
    float fgv[8];
    #pragma unroll
    for (int r = 0; r < 4; ++r) {
        int ch0 = w * 32 + kq * 4 + r;
        fgv[r]     = fgb[(size_t)ch0 * NS + n0 + col];
        fgv[4 + r] = fgb[(size_t)(ch0 + 16) * NS + n0 + col];
    }

    for (int i = t; i < 1536; i += 512) {
        int row = i / 96, c8 = (i % 96) * 8;
        *(bf16x8*)&GtT[row][c8] =
            *(const bf16x8*)&Gb[((size_t)b * NS + n0 + row) * DV + c8];
    }
    __syncthreads();

    // ---- GEMM1: K = 768 ----
    f32x4 acc0 = {0.f, 0.f, 0.f, 0.f};
    f32x4 acc1 = {0.f, 0.f, 0.f, 0.f};
    {
        const unsigned short* A0 = Wpb + (size_t)(w * 32 + col) * DV;
        const unsigned short* A1 = Wpb + (size_t)(w * 32 + 16 + col) * DV;
        #pragma unroll 4
        for (int ks = 0; ks < 24; ++ks) {
            int kb = ks * 32 + kq * 8;
            bf16x8 bf = *(const bf16x8*)&GtT[col][kb];
            bf16x8 a0 = *(const bf16x8*)&A0[kb];
            bf16x8 a1 = *(const bf16x8*)&A1[kb];
            acc0 = __builtin_amdgcn_mfma_f32_16x16x32_bf16(a0, bf, acc0, 0, 0, 0);
            acc1 = __builtin_amdgcn_mfma_f32_16x16x32_bf16(a1, bf, acc1, 0, 0, 0);
        }
    }

    // ---- bias + LayerNorm over channels ----
    float vals[8];
    float s = 0.f, q = 0.f;
    #pragma unroll
    for (int r = 0; r < 4; ++r) {
        int ch0 = w * 32 + kq * 4 + r;
        float v0 = acc0[r] + bp[ch0];
        float v1 = acc1[r] + bp[ch0 + 16];
        vals[r]     = v0;
        vals[4 + r] = v1;
        s += v0 + v1;
        q += v0 * v0 + v1 * v1;
    }
    s += __shfl_xor(s, 16); s += __shfl_xor(s, 32);
    q += __shfl_xor(q, 16); q += __shfl_xor(q, 32);
    if (l < 16) { LNs[w][l] = s; LNq[w][l] = q; }
    __syncthreads();
    float S = 0.f, Q = 0.f;
    #pragma unroll
    for (int ww = 0; ww < 8; ++ww) { S += LNs[ww][col]; Q += LNq[ww][col]; }
    float mu   = S * (1.0f / DC);
    float rstd = rsqrtf(Q * (1.0f / DC) - mu * mu + LN_EPS);
    {
        ushort4 p0, p1;
        p0.x = f2bf((vals[0] - mu) * rstd);
        p0.y = f2bf((vals[1] - mu) * rstd);
        p0.z = f2bf((vals[2] - mu) * rstd);
        p0.w = f2bf((vals[3] - mu) * rstd);
        p1.x = f2bf((vals[4] - mu) * rstd);
        p1.y = f2bf((vals[5] - mu) * rstd);
        p1.z = f2bf((vals[6] - mu) * rstd);
        p1.w = f2bf((vals[7] - mu) * rstd);
        *(ushort4*)&XT[col][w * 32 + kq * 4]      = p0;
        *(ushort4*)&XT[col][w * 32 + 16 + kq * 4] = p1;
    }
    __syncthreads();

    // ---- GEMM2: H = relu(W1 @ X_ln + b1) ----
    acc0 = (f32x4){0.f, 0.f, 0.f, 0.f};
    acc1 = (f32x4){0.f, 0.f, 0.f, 0.f};
    {
        const unsigned short* A0 = W1b + (size_t)(w * 32 + col) * DC;
        const unsigned short* A1 = W1b + (size_t)(w * 32 + 16 + col) * DC;
        #pragma unroll
        for (int ks = 0; ks < 8; ++ks) {
            int kb = ks * 32 + kq * 8;
            bf16x8 bf = *(const bf16x8*)&XT[col][kb];
            bf16x8 a0 = *(const bf16x8*)&A0[kb];
            bf16x8 a1 = *(const bf16x8*)&A1[kb];
            acc0 = __builtin_amdgcn_mfma_f32_16x16x32_bf16(a0, bf, acc0, 0, 0, 0);
            acc1 = __builtin_amdgcn_mfma_f32_16x16x32_bf16(a1, bf, acc1, 0, 0, 0);
        }
    }
    {
        ushort4 p0, p1;
        int ch0 = w * 32 + kq * 4;
        p0.x = f2bf(fmaxf(acc0[0] + b1[ch0 + 0], 0.f));
        p0.y = f2bf(fmaxf(acc0[1] + b1[ch0 + 1], 0.f));
        p0.z = f2bf(fmaxf(acc0[2] + b1[ch0 + 2], 0.f));
        p0.w = f2bf(fmaxf(acc0[3] + b1[ch0 + 3], 0.f));
        p1.x = f2bf(fmaxf(acc1[0] + b1[ch0 + 16], 0.f));
        p1.y = f2bf(fmaxf(acc1[1] + b1[ch0 + 17], 0.f));
        p1.z = f2bf(fmaxf(acc1[2] + b1[ch0 + 18], 0.f));
        p1.w = f2bf(fmaxf(acc1[3] + b1[ch0 + 19], 0.f));
        *(ushort4*)&HT[col][ch0]      = p0;
        *(ushort4*)&HT[col][ch0 + 16] = p1;
    }
    __syncthreads();

    // ---- GEMM3 + blend + store ----
    acc0 = (f32x4){0.f, 0.f, 0.f, 0.f};
    acc1 = (f32x4){0.f, 0.f, 0.f, 0.f};
    {
        const unsigned short* A0 = W2b + (size_t)(w * 32 + col) * DC;
        const unsigned short* A1 = W2b + (size_t)(w * 32 + 16 + col) * DC;
        #pragma unroll
        for (int ks = 0; ks < 8; ++ks) {
            int kb = ks * 32 + kq * 8;
            bf16x8 bf = *(const bf16x8*)&HT[col][kb];
            bf16x8 a0 = *(const bf16x8*)&A0[kb];
            bf16x8 a1 = *(const bf16x8*)&A1[kb];
            acc0 = __builtin_amdgcn_mfma_f32_16x16x32_bf16(a0, bf, acc0, 0, 0, 0);
            acc1 = __builtin_amdgcn_mfma_f32_16x16x32_bf16(a1, bf, acc1, 0, 0, 0);
        }
    }
    {
        float* ob = out + (size_t)b * DC * NS;
        #pragma unroll
        for (int r = 0; r < 4; ++r) {
            int ch0 = w * 32 + kq * 4 + r;
            int ch1 = ch0 + 16;
            size_t o0 = (size_t)ch0 * NS + n0 + col;
            size_t o1 = (size_t)ch1 * NS + n0 + col;
            ob[o0] = 0.5f * fgv[r]     + 0.5f * (acc0[r] + b2[ch0]);
            ob[o1] = 0.5f * fgv[4 + r] + 0.5f * (acc1[r] + b2[ch1]);
        }
    }
}

extern "C" void kernel_launch(void* const* d_in, const int* in_sizes, int n_in,
                              void* d_out, int out_size, void* d_ws, size_t ws_size,
                              hipStream_t stream)
{
    (void)in_sizes; (void)n_in; (void)out_size; (void)ws_size;
    const float* seed_xyz = (const float*)d_in[1];
    const float* pts      = (const float*)d_in[2];
    const float* feat     = (const float*)d_in[3];
    const float* fgn      = (const float*)d_in[4];
    const float* Wp       = (const float*)d_in[5];
    const float* bp       = (const float*)d_in[6];
    const float* W1       = (const float*)d_in[7];
    const float* b1       = (const float*)d_in[8];
    const float* W2       = (const float*)d_in[9];
    const float* b2       = (const float*)d_in[10];
    float* out = (float*)d_out;

    // workspace layout (16B aligned)
    char* ws = (char*)d_ws;
    int*            idx = (int*)ws;                              // 16 KB
    unsigned short* Wpb = (unsigned short*)(ws + 49152);         // 384 KB
    unsigned short* W1b = (unsigned short*)(ws + 442368);        // 128 KB
    unsigned short* W2b = (unsigned short*)(ws + 573440);        // 128 KB
    unsigned short* Gb  = (unsigned short*)(ws + 704512);        // 6.29 MB

    argmin_prep_kernel<<<dim3(832), dim3(256), 0, stream>>>(
        seed_xyz, pts, idx, Wp, W1, W2, Wpb, W1b, W2b);
    gather_kernel<<<dim3(256), dim3(512), 0, stream>>>(feat, idx, Gb);
    mega_kernel<<<dim3(BB * (NS / 16)), dim3(512), 0, stream>>>(
        Gb, fgn, Wpb, bp, W1b, b1, W2b, b2, out);
}

// Round 2
// 66.755 us; speedup vs baseline: 1.0356x; 1.0223x over previous
//
#include <hip/hip_runtime.h>
#include <hip/hip_bf16.h>
#include <math.h>

#define LN_EPS 1e-5f

constexpr int BB  = 4;
constexpr int NS  = 1024;
constexpr int KP  = 8192;
constexpr int DV  = 768;
constexpr int DC  = 256;

using bf16x8 = __attribute__((ext_vector_type(8))) short;
using f32x4  = __attribute__((ext_vector_type(4))) float;

static __device__ __forceinline__ unsigned short f2bf(float v) {
    __hip_bfloat16 h = __float2bfloat16(v);
    return *reinterpret_cast<unsigned short*>(&h);
}

// ---------------------------------------------------------------------------
// K1: blocks [0,512)   : argmin — 8 seeds/block, f64-exact ordering via the
//     monotone form |p|^2 - 2 s.p (normalization cancels in argmin).
//     blocks [512,832) : weight f32->bf16 conversion (1 float4/thread).
//     (unchanged from the verified kernel)
// ---------------------------------------------------------------------------
__global__ __launch_bounds__(256) void argmin_prep_kernel(
    const float* __restrict__ seed_xyz, const float* __restrict__ pts,
    int* __restrict__ out_idx,
    const float* __restrict__ Wp, const float* __restrict__ W1,
    const float* __restrict__ W2,
    unsigned short* __restrict__ Wpb, unsigned short* __restrict__ W1b,
    unsigned short* __restrict__ W2b)
{
    const int t = threadIdx.x;
    if (blockIdx.x >= 512) {
        int e  = (blockIdx.x - 512) * 256 + t;   // float4 id, 81920 total
        int e4 = e << 2;
        const float* src; unsigned short* dst; int off;
        if (e4 < DC * DV)              { src = Wp; dst = Wpb; off = e4; }
        else if (e4 < DC * (DV + DC))  { src = W1; dst = W1b; off = e4 - DC * DV; }
        else                           { src = W2; dst = W2b; off = e4 - DC * (DV + DC); }
        float4 v = *(const float4*)(src + off);
        ushort4 o;
        o.x = f2bf(v.x); o.y = f2bf(v.y); o.z = f2bf(v.z); o.w = f2bf(v.w);
        *(ushort4*)(dst + off) = o;
        return;
    }

    __shared__ float shX[1024], shY[1024], shZ[1024];
    __shared__ double rb[4][8];
    __shared__ int    ri[4][8];

    const int bid  = blockIdx.x;
    const int b    = bid >> 7;          // 128 tiles per batch
    const int tile = bid & 127;

    double n2sx[8], n2sy[8], n2sz[8];
    {
        const float* sp = seed_xyz + ((size_t)b * NS + tile * 8) * 3;
        #pragma unroll
        for (int ss = 0; ss < 8; ++ss) {
            n2sx[ss] = -2.0 * (double)sp[ss * 3 + 0];
            n2sy[ss] = -2.0 * (double)sp[ss * 3 + 1];
            n2sz[ss] = -2.0 * (double)sp[ss * 3 + 2];
        }
    }

    const float* pb = pts + (size_t)b * KP * 3;
    double best[8];
    int    bidx[8];
    #pragma unroll
    for (int ss = 0; ss < 8; ++ss) { best[ss] = 1e300; bidx[ss] = 0; }

    for (int kt = 0; kt < KP; kt += 1024) {
        #pragma unroll
        for (int q = 0; q < 4; ++q) {
            int i = t + q * 256;
            const float* pp = pb + (size_t)(kt + i) * 3;
            shX[i] = pp[0]; shY[i] = pp[1]; shZ[i] = pp[2];
        }
        __syncthreads();
        #pragma unroll 2
        for (int q = 0; q < 4; ++q) {
            int kl = t + (q << 8);
            double px = (double)shX[kl];
            double py = (double)shY[kl];
            double pz = (double)shZ[kl];
            double h  = fma(px, px, fma(py, py, pz * pz));
            #pragma unroll
            for (int ss = 0; ss < 8; ++ss) {
                double acc = fma(n2sx[ss], px, h);
                acc = fma(n2sy[ss], py, acc);
                acc = fma(n2sz[ss], pz, acc);
                if (acc < best[ss]) { best[ss] = acc; bidx[ss] = kt + kl; }
            }
        }
        __syncthreads();
    }

    #pragma unroll
    for (int o = 1; o < 64; o <<= 1) {
        #pragma unroll
        for (int ss = 0; ss < 8; ++ss) {
            double ob = __shfl_xor(best[ss], o);
            int    oi = __shfl_xor(bidx[ss], o);
            if (ob < best[ss] || (ob == best[ss] && oi < bidx[ss])) {
                best[ss] = ob; bidx[ss] = oi;
            }
        }
    }
    const int w = t >> 6, l = t & 63;
    if (l == 0) {
        #pragma unroll
        for (int ss = 0; ss < 8; ++ss) { rb[w][ss] = best[ss]; ri[w][ss] = bidx[ss]; }
    }
    __syncthreads();
    if (t < 8) {
        double bb = rb[0][t]; int bi = ri[0][t];
        #pragma unroll
        for (int ww = 1; ww < 4; ++ww) {
            double ob = rb[ww][t]; int oi = ri[ww][t];
            if (ob < bb || (ob == bb && oi < bi)) { bb = ob; bi = oi; }
        }
        out_idx[b * NS + tile * 8 + t] = bi;
    }
}

// ---------------------------------------------------------------------------
// K2: projection-first GEMM, replacing the scattered gather entirely.
// X_all = Wp(bf16) @ feat(bf16-on-the-fly) for ALL 8192 columns, reading feat
// fully coalesced (streaming, ~100 MB at HBM BW). Epilogue scatters only the
// needed columns (seeds whose argmin k lands in this block's 64-wide k-tile)
// as f32 into Xg[b][seed][ch]. Gather commutes with the linear projection,
// and the 24-step c-accumulation order is identical to the old fused GEMM1,
// so Xg is bitwise identical to the previous kernel's GEMM1 accumulator.
// grid = 4 b x 128 k-tiles = 512 blocks, 512 thr (2 blocks/CU, 16 waves/CU).
// LDS B-tile [64k][40c-stride] bf16 with XOR block swizzle
// q(krow)=((krow>>2)^(krow>>4))&3 -> ~2-way banks on both write and read.
// ---------------------------------------------------------------------------
__global__ __launch_bounds__(512, 4) void proj_kernel(
    const float* __restrict__ feat, const int* __restrict__ idx,
    const unsigned short* __restrict__ Wpb, float* __restrict__ Xg)
{
    __shared__ unsigned short LDSB[64 * 40];
    __shared__ int ent_s[1024];
    __shared__ int ent_k[1024];
    __shared__ int nent;

    const int bid = blockIdx.x;
    const int b   = bid >> 7;
    const int kt  = bid & 127;
    const int k0  = kt * 64;
    const int t   = threadIdx.x;
    const int w   = t >> 6;
    const int l   = t & 63;
    const int col = l & 15;
    const int kq  = l >> 4;

    if (t == 0) nent = 0;
    __syncthreads();
    // needed-seed list for this k-tile (order irrelevant: distinct seed rows)
    {
        int ka = idx[b * NS + t];
        int kb = idx[b * NS + 512 + t];
        if (ka >= k0 && ka < k0 + 64) { int p = atomicAdd(&nent, 1); ent_s[p] = t;       ent_k[p] = ka; }
        if (kb >= k0 && kb < k0 + 64) { int p = atomicAdd(&nent, 1); ent_s[p] = 512 + t; ent_k[p] = kb; }
    }
    // list consumed only after the K-loop barriers — no extra barrier needed.

    // staging map: cc = t>>4 (32 c-rows/step), k4 = t&15 -> kk = k4*4 (1 float4)
    const int cc = t >> 4;
    const int k4 = t & 15;
    const float* fbase = feat + ((size_t)b * DV + cc) * KP + k0 + k4 * 4;

    f32x4 acc0[4], acc1[4];
    #pragma unroll
    for (int kg = 0; kg < 4; ++kg) {
        acc0[kg] = (f32x4){0.f, 0.f, 0.f, 0.f};
        acc1[kg] = (f32x4){0.f, 0.f, 0.f, 0.f};
    }

    f32x4 r = *(const f32x4*)(fbase);            // step 0 prefetch
    for (int s = 0; s < 24; ++s) {
        if (s) __syncthreads();                  // prior step's LDS reads done
        {
            const int kr0 = k4 * 4;
            const int cb  = cc >> 3;
            const int cl  = cc & 7;
            #pragma unroll
            for (int i = 0; i < 4; ++i) {
                int krow = kr0 + i;
                int qv   = ((krow >> 2) ^ (krow >> 4)) & 3;
                LDSB[krow * 40 + ((cb ^ qv) << 3) + cl] = f2bf(r[i]);
            }
        }
        if (s + 1 < 24)                           // prefetch next c-step
            r = *(const f32x4*)(fbase + (size_t)(s + 1) * 32 * KP);
        __syncthreads();
        const unsigned short* A0 = Wpb + (size_t)(w * 32 + col) * DV + s * 32 + kq * 8;
        bf16x8 a0 = *(const bf16x8*)A0;
        bf16x8 a1 = *(const bf16x8*)(A0 + (size_t)16 * DV);
        #pragma unroll
        for (int kg = 0; kg < 4; ++kg) {
            int krow = kg * 16 + col;
            int qv   = ((krow >> 2) ^ (krow >> 4)) & 3;
            bf16x8 bf = *(const bf16x8*)&LDSB[krow * 40 + ((kq ^ qv) << 3)];
            acc0[kg] = __builtin_amdgcn_mfma_f32_16x16x32_bf16(a0, bf, acc0[kg], 0, 0, 0);
            acc1[kg] = __builtin_amdgcn_mfma_f32_16x16x32_bf16(a1, bf, acc1[kg], 0, 0, 0);
        }
    }
    __syncthreads();                              // entry list + accs final

    const int ne = nent;
    for (int e = 0; e < ne; ++e) {
        int sd = ent_s[e];
        int kk = ent_k[e] - k0;
        if (col == (kk & 15)) {
            int j = kk >> 4;
            float* dst = Xg + ((size_t)(b * NS + sd)) * DC + w * 32 + kq * 4;
            #pragma unroll
            for (int jj = 0; jj < 4; ++jj) if (jj == j) {
                *(f32x4*)dst        = acc0[jj];
                *(f32x4*)(dst + 16) = acc1[jj];
            }
        }
    }
}

// ---------------------------------------------------------------------------
// K3: mega kernel, GEMM1 removed. per block = (batch, 16 seeds), 8 waves.
// Reads Xg (f32, bitwise equal to old GEMM1 acc), adds bias, LN, GEMM2/3,
// blend. fg blend operand prefetched at kernel start.
// ---------------------------------------------------------------------------
__global__ __launch_bounds__(512) void mega_kernel(
    const float* __restrict__ Xg,
    const float* __restrict__ fg,
    const float* __restrict__ bp,
    const unsigned short* __restrict__ W1b, const float* __restrict__ b1,
    const unsigned short* __restrict__ W2b, const float* __restrict__ b2,
    float* __restrict__ out)
{
    __shared__ alignas(16) unsigned short XT[16][264];
    __shared__ alignas(16) unsigned short HT[16][264];
    __shared__ float LNs[8][16];
    __shared__ float LNq[8][16];

    const int bid  = blockIdx.x;
    const int b    = bid >> 6;
    const int tile = bid & 63;
    const int n0   = tile * 16;
    const int t    = threadIdx.x;
    const int w    = t >> 6;
    const int l    = t & 63;
    const int col  = l & 15;
    const int kq   = l >> 4;

    // prefetch blend operand (consumed in epilogue; latency hidden)
    const float* fgb = fg + (size_t)b * DC * NS;
    float fgv[8];
    #pragma unroll
    for (int r = 0; r < 4; ++r) {
        int ch0 = w * 32 + kq * 4 + r;
        fgv[r]     = fgb[(size_t)ch0 * NS + n0 + col];
        fgv[4 + r] = fgb[(size_t)(ch0 + 16) * NS + n0 + col];
    }

    // X values for this thread's 8 (seed=col, ch) slots, straight from Xg
    const float* xr = Xg + ((size_t)(b * NS + n0 + col)) * DC + w * 32 + kq * 4;
    f32x4 x0 = *(const f32x4*)xr;
    f32x4 x1 = *(const f32x4*)(xr + 16);

    // ---- bias + LayerNorm over channels ----
    float vals[8];
    float s = 0.f, q = 0.f;
    #pragma unroll
    for (int r = 0; r < 4; ++r) {
        int ch0 = w * 32 + kq * 4 + r;
        float v0 = x0[r] + bp[ch0];
        float v1 = x1[r] + bp[ch0 + 16];
        vals[r]     = v0;
        vals[4 + r] = v1;
        s += v0 + v1;
        q += v0 * v0 + v1 * v1;
    }
    s += __shfl_xor(s, 16); s += __shfl_xor(s, 32);
    q += __shfl_xor(q, 16); q += __shfl_xor(q, 32);
    if (l < 16) { LNs[w][l] = s; LNq[w][l] = q; }
    __syncthreads();
    float S = 0.f, Q = 0.f;
    #pragma unroll
    for (int ww = 0; ww < 8; ++ww) { S += LNs[ww][col]; Q += LNq[ww][col]; }
    float mu   = S * (1.0f / DC);
    float rstd = rsqrtf(Q * (1.0f / DC) - mu * mu + LN_EPS);
    {
        ushort4 p0, p1;
        p0.x = f2bf((vals[0] - mu) * rstd);
        p0.y = f2bf((vals[1] - mu) * rstd);
        p0.z = f2bf((vals[2] - mu) * rstd);
        p0.w = f2bf((vals[3] - mu) * rstd);
        p1.x = f2bf((vals[4] - mu) * rstd);
        p1.y = f2bf((vals[5] - mu) * rstd);
        p1.z = f2bf((vals[6] - mu) * rstd);
        p1.w = f2bf((vals[7] - mu) * rstd);
        *(ushort4*)&XT[col][w * 32 + kq * 4]      = p0;
        *(ushort4*)&XT[col][w * 32 + 16 + kq * 4] = p1;
    }
    __syncthreads();

    // ---- GEMM2: H = relu(W1 @ X_ln + b1) ----
    f32x4 acc0 = {0.f, 0.f, 0.f, 0.f};
    f32x4 acc1 = {0.f, 0.f, 0.f, 0.f};
    {
        const unsigned short* A0 = W1b + (size_t)(w * 32 + col) * DC;
        const unsigned short* A1 = W1b + (size_t)(w * 32 + 16 + col) * DC;
        #pragma unroll
        for (int ks = 0; ks < 8; ++ks) {
            int kb = ks * 32 + kq * 8;
            bf16x8 bf = *(const bf16x8*)&XT[col][kb];
            bf16x8 a0 = *(const bf16x8*)&A0[kb];
            bf16x8 a1 = *(const bf16x8*)&A1[kb];
            acc0 = __builtin_amdgcn_mfma_f32_16x16x32_bf16(a0, bf, acc0, 0, 0, 0);
            acc1 = __builtin_amdgcn_mfma_f32_16x16x32_bf16(a1, bf, acc1, 0, 0, 0);
        }
    }
    {
        ushort4 p0, p1;
        int ch0 = w * 32 + kq * 4;
        p0.x = f2bf(fmaxf(acc0[0] + b1[ch0 + 0], 0.f));
        p0.y = f2bf(fmaxf(acc0[1] + b1[ch0 + 1], 0.f));
        p0.z = f2bf(fmaxf(acc0[2] + b1[ch0 + 2], 0.f));
        p0.w = f2bf(fmaxf(acc0[3] + b1[ch0 + 3], 0.f));
        p1.x = f2bf(fmaxf(acc1[0] + b1[ch0 + 16], 0.f));
        p1.y = f2bf(fmaxf(acc1[1] + b1[ch0 + 17], 0.f));
        p1.z = f2bf(fmaxf(acc1[2] + b1[ch0 + 18], 0.f));
        p1.w = f2bf(fmaxf(acc1[3] + b1[ch0 + 19], 0.f));
        *(ushort4*)&HT[col][ch0]      = p0;
        *(ushort4*)&HT[col][ch0 + 16] = p1;
    }
    __syncthreads();

    // ---- GEMM3 + blend + store ----
    acc0 = (f32x4){0.f, 0.f, 0.f, 0.f};
    acc1 = (f32x4){0.f, 0.f, 0.f, 0.f};
    {
        const unsigned short* A0 = W2b + (size_t)(w * 32 + col) * DC;
        const unsigned short* A1 = W2b + (size_t)(w * 32 + 16 + col) * DC;
        #pragma unroll
        for (int ks = 0; ks < 8; ++ks) {
            int kb = ks * 32 + kq * 8;
            bf16x8 bf = *(const bf16x8*)&HT[col][kb];
            bf16x8 a0 = *(const bf16x8*)&A0[kb];
            bf16x8 a1 = *(const bf16x8*)&A1[kb];
            acc0 = __builtin_amdgcn_mfma_f32_16x16x32_bf16(a0, bf, acc0, 0, 0, 0);
            acc1 = __builtin_amdgcn_mfma_f32_16x16x32_bf16(a1, bf, acc1, 0, 0, 0);
        }
    }
    {
        float* ob = out + (size_t)b * DC * NS;
        #pragma unroll
        for (int r = 0; r < 4; ++r) {
            int ch0 = w * 32 + kq * 4 + r;
            int ch1 = ch0 + 16;
            size_t o0 = (size_t)ch0 * NS + n0 + col;
            size_t o1 = (size_t)ch1 * NS + n0 + col;
            ob[o0] = 0.5f * fgv[r]     + 0.5f * (acc0[r] + b2[ch0]);
            ob[o1] = 0.5f * fgv[4 + r] + 0.5f * (acc1[r] + b2[ch1]);
        }
    }
}

extern "C" void kernel_launch(void* const* d_in, const int* in_sizes, int n_in,
                              void* d_out, int out_size, void* d_ws, size_t ws_size,
                              hipStream_t stream)
{
    (void)in_sizes; (void)n_in; (void)out_size; (void)ws_size;
    const float* seed_xyz = (const float*)d_in[1];
    const float* pts      = (const float*)d_in[2];
    const float* feat     = (const float*)d_in[3];
    const float* fgn      = (const float*)d_in[4];
    const float* Wp       = (const float*)d_in[5];
    const float* bp       = (const float*)d_in[6];
    const float* W1       = (const float*)d_in[7];
    const float* b1       = (const float*)d_in[8];
    const float* W2       = (const float*)d_in[9];
    const float* b2       = (const float*)d_in[10];
    float* out = (float*)d_out;

    // workspace layout (16B aligned):
    //   idx  @ 0        (16 KB)
    //   Wpb  @ 16384    (384 KB)
    //   W1b  @ 409600   (128 KB)
    //   W2b  @ 540672   (128 KB)
    //   Xg   @ 671744   (4.19 MB f32 [B][NS][DC])
    char* ws = (char*)d_ws;
    int*            idx = (int*)ws;
    unsigned short* Wpb = (unsigned short*)(ws + 16384);
    unsigned short* W1b = (unsigned short*)(ws + 409600);
    unsigned short* W2b = (unsigned short*)(ws + 540672);
    float*          Xg  = (float*)(ws + 671744);

    argmin_prep_kernel<<<dim3(832), dim3(256), 0, stream>>>(
        seed_xyz, pts, idx, Wp, W1, W2, Wpb, W1b, W2b);
    proj_kernel<<<dim3(512), dim3(512), 0, stream>>>(feat, idx, Wpb, Xg);
    mega_kernel<<<dim3(BB * (NS / 16)), dim3(512), 0, stream>>>(
        Xg, fgn, bp, W1b, b1, W2b, b2, out);
}